// Round 1
// 763.953 us; speedup vs baseline: 1.0006x; 1.0006x over previous
//
#include <hip/hip_runtime.h>
#include <hip/hip_bf16.h>

// Problem constants (from reference): N=16384, C=10000, D=128, LR=0.5
#define N_SAMPLES 16384
#define N_CLASSES 10000
#define DIM 128
#define LR_CONST 0.5f
#define NVEC 2500    // float4 per labels row
#define CHUNK 64     // float4 per wave-chunk (256 floats = 1 KB)
#define MAXK 64      // per-class sample-list capacity (max realistic count ~10)

typedef float f32x4 __attribute__((ext_vector_type(4)));

__device__ __forceinline__ int clampj(int j) { return j > NVEC - 1 ? NVEC - 1 : j; }

// One wave per sample row: depth-4 pipelined one-hot scan. Each wave keeps
// 4 KB (4 chunks) in flight so per-wave throughput = inflight/latency stays
// above HBM-saturation share even with queue-inflated latency (the depth-1
// version was latency-bound at ~1 TB/s effective). On hit: push sample index
// onto its class's list (16K single int atomics total).
__global__ __launch_bounds__(256) void scan_kernel(
    const float* __restrict__ labels,   // [N, C]
    int* __restrict__ counts,           // [C]        (pre-zeroed)
    int* __restrict__ lists)            // [C, MAXK]
{
    const int lane = threadIdx.x & 63;
    const int n = blockIdx.x * 4 + (threadIdx.x >> 6);  // 4096 blocks x 4 waves

    const f32x4* row = reinterpret_cast<const f32x4*>(labels + (size_t)n * N_CLASSES);

    // Prologue: chunks 0..3 in flight (indices <= 255, no clamp needed).
    int j0 = lane;
    int j1 = CHUNK + lane;
    int j2 = 2 * CHUNK + lane;
    int j3 = 3 * CHUNK + lane;
    f32x4 u0 = __builtin_nontemporal_load(row + j0);
    f32x4 u1 = __builtin_nontemporal_load(row + j1);
    f32x4 u2 = __builtin_nontemporal_load(row + j2);
    f32x4 u3 = __builtin_nontemporal_load(row + j3);

    int c = -1;

    for (int cb = 0; cb < NVEC; cb += 4 * CHUNK) {
        // Issue the NEXT 4 chunks before testing the current 4 (ring depth 4).
        const int p0 = clampj(cb + 4 * CHUNK + lane);
        const int p1 = clampj(cb + 5 * CHUNK + lane);
        const int p2 = clampj(cb + 6 * CHUNK + lane);
        const int p3 = clampj(cb + 7 * CHUNK + lane);
        const f32x4 v0 = __builtin_nontemporal_load(row + p0);
        const f32x4 v1 = __builtin_nontemporal_load(row + p1);
        const f32x4 v2 = __builtin_nontemporal_load(row + p2);
        const f32x4 v3 = __builtin_nontemporal_load(row + p3);

        // One-hot values are exact 0.0f/1.0f: sum>0.5 iff this lane's 16B
        // holds the 1. Ballot is wave-uniform -> uniform branch; comp is
        // resolved only via shfl from the first hit lane (clamped duplicate
        // lanes agree on the same class).
#define TEST_CHUNK(u, j) do {                                                   \
        const unsigned long long m_ =                                           \
            __ballot((u).x + (u).y + (u).z + (u).w > 0.5f);                     \
        if (m_) {                                                               \
            const int comp_ = ((u).y > 0.5f) ? 1                                \
                            : ((u).z > 0.5f) ? 2                                \
                            : ((u).w > 0.5f) ? 3 : 0;                           \
            c = __shfl(4 * (j) + comp_, (int)(__ffsll(m_) - 1));                \
            goto found;                                                         \
        } } while (0)

        TEST_CHUNK(u0, j0);
        TEST_CHUNK(u1, j1);
        TEST_CHUNK(u2, j2);
        TEST_CHUNK(u3, j3);
#undef TEST_CHUNK

        u0 = v0; u1 = v1; u2 = v2; u3 = v3;
        j0 = p0; j1 = p1; j2 = p2; j3 = p3;
    }
    return;  // safety only; one-hot guarantees a hit

found:
    if (lane == 0) {
        int slot = atomicAdd(&counts[c], 1);
        if (slot < MAXK) lists[c * MAXK + slot] = n;
    }
}

// One wave per class: out[c,:] = center - LR*(k*center - sum(preds[n,:]))/(k+1)
// (algebraically identical to reference grad = sum(center - pred) / (k+1)).
__global__ __launch_bounds__(256) void finalize_kernel(
    const float* __restrict__ preds,    // [N, D]
    const float* __restrict__ center,   // [C, D]
    const int* __restrict__ counts,     // [C]
    const int* __restrict__ lists,      // [C, MAXK]
    float* __restrict__ out)            // [C, D]
{
    const int lane = threadIdx.x & 63;
    const int c = blockIdx.x * 4 + (threadIdx.x >> 6);  // 2500 blocks x 4 waves
    if (c >= N_CLASSES) return;

    const int k = counts[c];
    float s0 = 0.0f, s1 = 0.0f;
    for (int i = 0; i < k; ++i) {
        const int n = lists[c * MAXK + i];          // wave-uniform load
        const float* p = preds + (size_t)n * DIM;
        s0 += p[lane];
        s1 += p[64 + lane];
    }

    const float kf = (float)k;
    const float inv = 1.0f / (kf + 1.0f);
    const size_t cb = (size_t)c * DIM;
    const float c0 = center[cb + lane];
    const float c1 = center[cb + 64 + lane];
    const float v0 = c0 - LR_CONST * (kf * c0 - s0) * inv;
    const float v1 = c1 - LR_CONST * (kf * c1 - s1) * inv;
    __builtin_nontemporal_store(v0, out + cb + lane);
    __builtin_nontemporal_store(v1, out + cb + 64 + lane);
}

extern "C" void kernel_launch(void* const* d_in, const int* in_sizes, int n_in,
                              void* d_out, int out_size, void* d_ws, size_t ws_size,
                              hipStream_t stream) {
    const float* preds  = (const float*)d_in[0];  // [N, D]
    const float* labels = (const float*)d_in[1];  // [N, C]
    const float* center = (const float*)d_in[2];  // [C, D]
    float* out = (float*)d_out;                   // [C, D]

    // Workspace layout: counts [C] i32 | lists [C*MAXK] i32
    int* counts = (int*)d_ws;
    int* lists  = counts + N_CLASSES;

    // Zero only the counts (40 KB); lists don't need init.
    hipMemsetAsync(counts, 0, (size_t)N_CLASSES * sizeof(int), stream);

    scan_kernel<<<N_SAMPLES / 4, 256, 0, stream>>>(labels, counts, lists);

    finalize_kernel<<<(N_CLASSES + 3) / 4, 256, 0, stream>>>(preds, center, counts, lists, out);
}